// Round 5
// baseline (258.613 us; speedup 1.0000x reference)
//
#include <hip/hip_runtime.h>
#include <hip/hip_bf16.h>
#include <math.h>

// Problem constants
#define BB 4
#define NN 2048
#define DIM 384
#define HEADS 8
#define HD 48
#define MLPH 1536
#define ROWS (BB*NN)          // 8192
#define SZ ((size_t)ROWS*DIM) // 3145728 elems per (B,N,DIM) buffer

typedef float floatx4 __attribute__((ext_vector_type(4)));
typedef short shortx8 __attribute__((ext_vector_type(8)));

__device__ __forceinline__ float gelu_exact(float x) {
    return 0.5f * x * (1.0f + erff(x * 0.70710678118654752f));
}

__device__ __forceinline__ short f2bf(float f) {
    __hip_bfloat16 h = __float2bfloat16(f);
    return *reinterpret_cast<short*>(&h);
}

// packed f32x2 -> bf16x2 in one VALU op (low = a, high = b)
__device__ __forceinline__ unsigned cvtpk(float a, float b) {
    unsigned r;
    asm("v_cvt_pk_bf16_f32 %0, %1, %2" : "=v"(r) : "v"(a), "v"(b));
    return r;
}
__device__ __forceinline__ short f2bf_c(float f) {
    return (short)((__float_as_uint(f) + 0x8000u) >> 16);
}

// async global->LDS 16B: linear LDS dest (base + lane*16), per-lane global src
typedef __attribute__((address_space(3))) void lds_void;
typedef const __attribute__((address_space(1))) void gbl_void;
__device__ __forceinline__ void gload16(const void* g, void* l) {
    __builtin_amdgcn_global_load_lds((gbl_void*)g, (lds_void*)l, 16, 0, 0);
}

// softmax scale folded with log2(e): q is pre-scaled so attn uses bare exp2
#define SCALE_Q 0.20823510128640994f  // (1/sqrt(48)) * log2(e)

// ---------------- LayerNorm: 4 rows/block (one wave each), fp32 -> bf16 ----------------
__global__ __launch_bounds__(256) void ln_bf16_kernel(const float* __restrict__ x,
                                                      const float* __restrict__ g,
                                                      const float* __restrict__ be,
                                                      short* __restrict__ out) {
    int row = blockIdx.x * 4 + (threadIdx.x >> 6);
    int lane = threadIdx.x & 63;
    const float* xp = x + (size_t)row * DIM;
    float v[6];
    float sum = 0.f, sumsq = 0.f;
#pragma unroll
    for (int j = 0; j < 6; j++) {
        float val = xp[lane + j * 64];
        v[j] = val; sum += val; sumsq += val * val;
    }
#pragma unroll
    for (int off = 1; off < 64; off <<= 1) {
        sum += __shfl_xor(sum, off, 64);
        sumsq += __shfl_xor(sumsq, off, 64);
    }
    float mean = sum * (1.f / DIM);
    float var = sumsq * (1.f / DIM) - mean * mean;
    float rstd = rsqrtf(var + 1e-5f);
    short* op = out + (size_t)row * DIM;
#pragma unroll
    for (int j = 0; j < 6; j++) {
        int c = lane + j * 64;
        op[c] = f2bf((v[j] - mean) * rstd * g[c] + be[c]);
    }
}

// ---------------- fused head: weight transposes + bias concat + LN1 + pos-MLP ----------
__global__ __launch_bounds__(256) void head_kernel(const float* __restrict__ Wq,
                                                   const float* __restrict__ Wk,
                                                   const float* __restrict__ Wv,
                                                   const float* __restrict__ Wo,
                                                   const float* __restrict__ mw1,
                                                   const float* __restrict__ mw2,
                                                   const float* __restrict__ bq,
                                                   const float* __restrict__ bk,
                                                   const float* __restrict__ bv,
                                                   const float* __restrict__ x,
                                                   const float* __restrict__ g1,
                                                   const float* __restrict__ be1,
                                                   const float* __restrict__ pos,
                                                   const float* __restrict__ pw1,
                                                   const float* __restrict__ pb1,
                                                   const float* __restrict__ pw2,
                                                   const float* __restrict__ pb2,
                                                   short* __restrict__ Wqkv_t,
                                                   short* __restrict__ Wo_t,
                                                   short* __restrict__ mw1_t,
                                                   short* __restrict__ mw2_t,
                                                   float* __restrict__ bqkv,
                                                   short* __restrict__ h_bf,
                                                   float* __restrict__ pe) {
    __shared__ float tile[32][33];
    __shared__ float pw2s[HD * HD];
    __shared__ float hsh[4][HD];
    const int id = blockIdx.x;
    const int t = threadIdx.x;
    if (id < 1728) {
        const float* src; short* dst; int K, N, tid;
        if (id < 144)       { src = Wq;  dst = Wqkv_t;          K = 384;  N = 384;  tid = id; }
        else if (id < 288)  { src = Wk;  dst = Wqkv_t + 147456; K = 384;  N = 384;  tid = id - 144; }
        else if (id < 432)  { src = Wv;  dst = Wqkv_t + 294912; K = 384;  N = 384;  tid = id - 288; }
        else if (id < 576)  { src = Wo;  dst = Wo_t;            K = 384;  N = 384;  tid = id - 432; }
        else if (id < 1152) { src = mw1; dst = mw1_t;           K = 384;  N = 1536; tid = id - 576; }
        else                { src = mw2; dst = mw2_t;           K = 1536; N = 384;  tid = id - 1152; }
        int ntx = N / 32;
        int n0 = (tid % ntx) * 32, k0 = (tid / ntx) * 32;
        int c = t & 31, r4 = t >> 5;
#pragma unroll
        for (int i = 0; i < 4; i++) {
            int r = r4 + i * 8;
            tile[r][c] = src[(size_t)(k0 + r) * N + n0 + c];
        }
        __syncthreads();
#pragma unroll
        for (int i = 0; i < 4; i++) {
            int r = r4 + i * 8;
            dst[(size_t)(n0 + r) * K + k0 + c] = f2bf(tile[c][r]);
        }
    } else if (id == 1728) {
        for (int i = t; i < 3 * DIM; i += 256)
            bqkv[i] = i < DIM ? bq[i] : (i < 2 * DIM ? bk[i - DIM] : bv[i - 2 * DIM]);
    } else if (id < 3777) {
        int row = (id - 1729) * 4 + (t >> 6);
        int lane = t & 63;
        const float* xp = x + (size_t)row * DIM;
        float v[6];
        float sum = 0.f, sumsq = 0.f;
#pragma unroll
        for (int j = 0; j < 6; j++) {
            float val = xp[lane + j * 64];
            v[j] = val; sum += val; sumsq += val * val;
        }
#pragma unroll
        for (int off = 1; off < 64; off <<= 1) {
            sum += __shfl_xor(sum, off, 64);
            sumsq += __shfl_xor(sumsq, off, 64);
        }
        float mean = sum * (1.f / DIM);
        float var = sumsq * (1.f / DIM) - mean * mean;
        float rstd = rsqrtf(var + 1e-5f);
        short* op = h_bf + (size_t)row * DIM;
#pragma unroll
        for (int j = 0; j < 6; j++) {
            int c = lane + j * 64;
            op[c] = f2bf((v[j] - mean) * rstd * g1[c] + be1[c]);
        }
    } else {
        int w = t >> 6, lane = t & 63;
        int p = (id - 3777) * 4 + w;
        for (int i = t; i < HD * HD; i += 256) pw2s[i] = pw2[i];
        float px = pos[(size_t)p * 3 + 0];
        float py = pos[(size_t)p * 3 + 1];
        float pz = pos[(size_t)p * 3 + 2];
        __syncthreads();
        if (lane < HD) {
            float hv = px * pw1[0 * HD + lane] + py * pw1[1 * HD + lane] + pz * pw1[2 * HD + lane] + pb1[lane];
            hsh[w][lane] = gelu_exact(hv);
        }
        if (lane < HD) {
            float o = pb2[lane];
#pragma unroll 8
            for (int i = 0; i < HD; i++) o += hsh[w][i] * pw2s[i * HD + lane];
            pe[(size_t)p * HD + lane] = o;
        }
    }
}

// ---------------- bf16 MFMA GEMM v8: 3-buffer, 2-ahead DMA, counted vmcnt -----------
// Same 64x64 tiles/grids/reads/epilogues as gemm5/7, but the K-loop is a depth-2
// pipeline (T3/T4): stage s+2 issued while computing s, and the per-step wait is
// s_waitcnt vmcnt(4) (NOT the vmcnt(0) drain __syncthreads emits) + raw s_barrier.
// vmcnt(4): newest stage (4 DMA loads) stays in flight, older stage guaranteed
// landed; barrier makes per-wave vmcnt collective. sched_barrier(0) pins the next
// STAGE below the barrier (buffer-reuse race guard). K is a template constant so
// the unrolled loop picks vmcnt(0) only on the final step.
// MODE 0: QKV fused -> q/k row-major bf16 (q pre-scaled by SCALE_Q; pe added to k),
//         V^T permuted (key_new = 4*(key%16)+key/16 per 64-key tile).
// MODE 1: exact gelu -> bf16 (MLP1)
// MODE 2: of = res + (mask ? v : 0)  fp32 (Wo + residual)
// MODE 3: of = mask ? (res + v) : 0  fp32 (MLP2 + residual + mask)
template <int MODE, int KK>
__global__ __launch_bounds__(256) void gemm8_kernel(const short* __restrict__ A,
                                                    const short* __restrict__ Bt,
                                                    const float* __restrict__ bias,
                                                    const float* __restrict__ pe,
                                                    const float* __restrict__ res,
                                                    const int* __restrict__ mask,
                                                    float* __restrict__ of,
                                                    short* __restrict__ o0,
                                                    short* __restrict__ o1,
                                                    short* __restrict__ o2,
                                                    int M, int N) {
    constexpr int NSTEP = KK / 64;
    __shared__ short As[3][64 * 64];
    __shared__ short Bs[3][64 * 64];
    const int t = threadIdx.x, lane = t & 63, w = t >> 6;
    const int l16 = lane & 15, quad = lane >> 4;
    const int m0 = blockIdx.y * 64, n0 = blockIdx.x * 64;
    const int wm = (w & 1) * 32, wn = (w >> 1) * 32;

    // staging: wave w covers tile rows [w*16, w*16+16), 2 DMA instrs each for A and B.
    // lane ll -> row w*16 + i*8 + (ll>>3), LDS chunk ll&7 (linear),
    // global chunk (ll&7)^(ll>>3)  [inverse swizzle -> content matches (c^(r&7)) reads]
    const int rA = lane >> 3;
    const int csw = ((lane & 7) ^ rA) * 8;
    const short* gA0 = A + (size_t)(m0 + w * 16 + rA) * KK + csw;
    const short* gA1 = gA0 + (size_t)8 * KK;
    const short* gB0 = Bt + (size_t)(n0 + w * 16 + rA) * KK + csw;
    const short* gB1 = gB0 + (size_t)8 * KK;
    const int ldsb = w * 16 * 64;   // wave's row base (shorts)

    floatx4 acc[2][2] = {};
    const int sA = l16 & 7;

#define STAGE8(buf, k0off)                                  \
    do {                                                    \
        gload16(gA0 + (k0off), &As[buf][ldsb]);             \
        gload16(gA1 + (k0off), &As[buf][ldsb + 8 * 64]);    \
        gload16(gB0 + (k0off), &Bs[buf][ldsb]);             \
        gload16(gB1 + (k0off), &Bs[buf][ldsb + 8 * 64]);    \
    } while (0)

    STAGE8(0, 0);
    if (NSTEP > 1) STAGE8(1, 64);
#pragma unroll
    for (int s = 0; s < NSTEP; s++) {
        if (s + 1 < NSTEP) asm volatile("s_waitcnt vmcnt(4)" ::: "memory");
        else               asm volatile("s_waitcnt vmcnt(0)" ::: "memory");
        __builtin_amdgcn_s_barrier();
        __builtin_amdgcn_sched_barrier(0);
        if (s + 2 < NSTEP) STAGE8((s + 2) % 3, (s + 2) * 64);
        const short* Ac = As[s % 3];
        const short* Bc = Bs[s % 3];
#pragma unroll
        for (int kkc = 0; kkc < 2; kkc++) {
            shortx8 af[2], bfr[2];
            int slot = ((quad + kkc * 4) ^ sA) * 8;
#pragma unroll
            for (int i = 0; i < 2; i++) {
                af[i]  = *(const shortx8*)&Ac[(wm + i * 16 + l16) * 64 + slot];
                bfr[i] = *(const shortx8*)&Bc[(wn + i * 16 + l16) * 64 + slot];
            }
#pragma unroll
            for (int mi = 0; mi < 2; mi++)
#pragma unroll
                for (int ni = 0; ni < 2; ni++)
                    acc[mi][ni] = __builtin_amdgcn_mfma_f32_16x16x32_bf16(af[mi], bfr[ni], acc[mi][ni], 0, 0, 0);
        }
    }
#undef STAGE8

    // epilogue: C row = m0+wm+mi*16+quad*4+reg, col = n0+wn+ni*16+l16
    const int seg = (MODE == 0) ? (n0 / DIM) : 0;
#pragma unroll
    for (int mi = 0; mi < 2; mi++) {
        int mrow0 = m0 + wm + mi * 16 + quad * 4;
        int4 mk4 = {0, 0, 0, 0};
        if (MODE == 2 || MODE == 3) mk4 = *(const int4*)&mask[mrow0];
#pragma unroll
        for (int ni = 0; ni < 2; ni++) {
            int n = n0 + wn + ni * 16 + l16;
            float bv = bias[n];
            float vals[4];
#pragma unroll
            for (int reg = 0; reg < 4; reg++) vals[reg] = acc[mi][ni][reg] + bv;
            if (MODE == 0) {
                int nl = n - seg * DIM;
                if (seg == 2) {
                    // V^T [b,h,d,T*64+key_new], key_new = 4*(key%16)+key/16
                    int hh = nl / HD, d = nl - hh * HD;
                    int bb = mrow0 / NN, nb = mrow0 - bb * NN;
                    int T = nb >> 6, ko = nb & 63;
                    int c16 = ko & 15, kb = ko >> 4;
                    short* vp = o2 + ((size_t)((bb * HEADS + hh) * HD + d)) * NN + T * 64 + kb;
#pragma unroll
                    for (int reg = 0; reg < 4; reg++) vp[4 * (c16 + reg)] = f2bf(vals[reg]);
                } else {
                    short* dstq = (seg == 0) ? o0 : o1;
                    int pc = nl % HD;
#pragma unroll
                    for (int reg = 0; reg < 4; reg++) {
                        int m = mrow0 + reg;
                        float val = vals[reg];
                        if (seg == 0) val *= SCALE_Q;       // fold softmax scale + log2e into q
                        if (seg == 1) val += pe[(size_t)m * HD + pc];
                        dstq[(size_t)m * DIM + nl] = f2bf(val);
                    }
                }
            } else if (MODE == 1) {
#pragma unroll
                for (int reg = 0; reg < 4; reg++)
                    o0[(size_t)(mrow0 + reg) * N + n] = f2bf(gelu_exact(vals[reg]));
            } else if (MODE == 2) {
#pragma unroll
                for (int reg = 0; reg < 4; reg++) {
                    int m = mrow0 + reg;
                    int mk = ((const int*)&mk4)[reg];
                    of[(size_t)m * N + n] = res[(size_t)m * N + n] + (mk ? vals[reg] : 0.f);
                }
            } else {
#pragma unroll
                for (int reg = 0; reg < 4; reg++) {
                    int m = mrow0 + reg;
                    int mk = ((const int*)&mk4)[reg];
                    of[(size_t)m * N + n] = mk ? (res[(size_t)m * N + n] + vals[reg]) : 0.f;
                }
            }
        }
    }
}

// ---------------- MFMA flash attention v8: exp2-domain softmax, mask in C-init --------
// q arrives pre-scaled by (1/sqrt(HD))*log2(e):
//   P = exp2(q'.k + ad),  ad = 0 / -1e30  (key-mask bias, folded into MFMA C input
//   since C/D col = l16 = key is lane-constant). bf16 pack via v_cvt_pk_bf16_f32.
__global__ __launch_bounds__(256) void attn7_kernel(const short* __restrict__ q,
                                                    const short* __restrict__ k,
                                                    const short* __restrict__ vt,
                                                    const int* __restrict__ mask,
                                                    short* __restrict__ out) {
    const int b = blockIdx.z, h = blockIdx.y;
    const int q0 = blockIdx.x * 128;
    const int t = threadIdx.x;
    const int lane = t & 63;
    const int w = t >> 6;
    const int l16 = lane & 15;
    const int quad = lane >> 4;

    __shared__ __align__(16) short SH[23552];
    __shared__ float madd2[2][64];

    {
        int buf = t >> 7, r = (t >> 1) & 63, zc = 6 + (t & 1);
        shortx8 z = {0, 0, 0, 0, 0, 0, 0, 0};
        *(shortx8*)&SH[buf * 4096 + r * 64 + ((zc ^ (r & 7)) * 8)] = z;
    }

    const size_t vtbase = (size_t)((b * HEADS + h) * HD) * NN;
    const short* gsrc[3]; int loff[3]; int gstep[3]; int bstr[3];
#pragma unroll
    for (int i = 0; i < 3; i++) {
        int u = t + i * 256;
        if (u < 384) {
            int r = u / 6, c = u - r * 6;
            gsrc[i] = k + ((size_t)(b * NN + r)) * DIM + h * HD + c * 8;
            gstep[i] = 64 * DIM;
            loff[i] = r * 64 + ((c ^ (r & 7)) * 8);
            bstr[i] = 4096;
        } else {
            int uu = u - 384;
            int d = uu >> 3, ck = uu & 7;
            gsrc[i] = vt + vtbase + (size_t)d * NN + ck * 8;
            gstep[i] = 64;
            loff[i] = 8192 + d * 64 + ((ck ^ (d & 7)) * 8);
            bstr[i] = 3072;
        }
    }

    shortx8 pre[3];
#pragma unroll
    for (int i = 0; i < 3; i++) pre[i] = *(const shortx8*)gsrc[i];
#pragma unroll
    for (int i = 0; i < 3; i++) *(shortx8*)&SH[loff[i]] = pre[i];
    if (t < 64) madd2[0][t] = mask[b * NN + t] ? 0.f : -1e30f;
#pragma unroll
    for (int i = 0; i < 3; i++) { gsrc[i] += gstep[i]; pre[i] = *(const shortx8*)gsrc[i]; }
    int mreg = (t < 64) ? mask[b * NN + 64 + t] : 0;

    shortx8 qf[2][2];
#pragma unroll
    for (int mt = 0; mt < 2; mt++) {
        const short* qp = q + ((size_t)(b * NN + q0 + w * 32 + mt * 16 + l16)) * DIM + h * HD;
        qf[mt][0] = *(const shortx8*)&qp[quad * 8];
        if (quad < 2) qf[mt][1] = *(const shortx8*)&qp[32 + quad * 8];
        else          qf[mt][1] = (shortx8){0, 0, 0, 0, 0, 0, 0, 0};
    }

    floatx4 acc[2][3] = {};
    float lsum[2][4] = {};
    const int plb = 14336 + w * 2304;
    const int sw = (l16 & 7);

    __syncthreads();

    for (int kt = 0; kt < 32; kt++) {
        const int cur = kt & 1, nxt = cur ^ 1;
        const int kso = cur * 4096, vto = 8192 + cur * 3072;

        shortx8 kb[4][2];
#pragma unroll
        for (int nt = 0; nt < 4; nt++) {
            int r = nt * 16 + l16;
            kb[nt][0] = *(const shortx8*)&SH[kso + r * 64 + ((quad ^ sw) * 8)];
            kb[nt][1] = *(const shortx8*)&SH[kso + r * 64 + (((4 + quad) ^ sw) * 8)];
        }
        float ad[4];
#pragma unroll
        for (int nt = 0; nt < 4; nt++) ad[nt] = madd2[cur][nt * 16 + l16];

        if (kt < 31) {
#pragma unroll
            for (int i = 0; i < 3; i++) *(shortx8*)&SH[loff[i] + nxt * bstr[i]] = pre[i];
            if (t < 64) madd2[nxt][t] = mreg ? 0.f : -1e30f;
            if (kt < 30) {
#pragma unroll
                for (int i = 0; i < 3; i++) { gsrc[i] += gstep[i]; pre[i] = *(const shortx8*)gsrc[i]; }
                if (t < 64) mreg = mask[b * NN + (kt + 2) * 64 + t];
            }
        }

        floatx4 S[2][4];
        __builtin_amdgcn_s_setprio(1);
#pragma unroll
        for (int nt = 0; nt < 4; nt++) {
            floatx4 ci = {ad[nt], ad[nt], ad[nt], ad[nt]};
#pragma unroll
            for (int mt = 0; mt < 2; mt++) {
                floatx4 s = __builtin_amdgcn_mfma_f32_16x16x32_bf16(qf[mt][0], kb[nt][0], ci, 0, 0, 0);
                s = __builtin_amdgcn_mfma_f32_16x16x32_bf16(qf[mt][1], kb[nt][1], s, 0, 0, 0);
                S[mt][nt] = s;
            }
        }
        __builtin_amdgcn_s_setprio(0);
#pragma unroll
        for (int mt = 0; mt < 2; mt++) {
            float p[4][4];
#pragma unroll
            for (int nt = 0; nt < 4; nt++) {
#pragma unroll
                for (int reg = 0; reg < 4; reg++) {
                    float pv = __builtin_amdgcn_exp2f(S[mt][nt][reg]);
                    p[nt][reg] = pv;
                    lsum[mt][reg] += pv;
                }
            }
#pragma unroll
            for (int reg = 0; reg < 4; reg++) {
                *(uint2*)&SH[plb + (mt * 16 + quad * 4 + reg) * 72 + l16 * 4] =
                    make_uint2(cvtpk(p[0][reg], p[1][reg]), cvtpk(p[2][reg], p[3][reg]));
            }
        }
        __builtin_amdgcn_s_setprio(1);
#pragma unroll
        for (int c = 0; c < 2; c++) {
            shortx8 pf[2];
#pragma unroll
            for (int mt = 0; mt < 2; mt++)
                pf[mt] = *(const shortx8*)&SH[plb + (mt * 16 + l16) * 72 + c * 32 + quad * 8];
#pragma unroll
            for (int dt = 0; dt < 3; dt++) {
                shortx8 vf = *(const shortx8*)&SH[vto + (dt * 16 + l16) * 64 + (((c * 4 + quad) ^ sw) * 8)];
#pragma unroll
                for (int mt = 0; mt < 2; mt++)
                    acc[mt][dt] = __builtin_amdgcn_mfma_f32_16x16x32_bf16(pf[mt], vf, acc[mt][dt], 0, 0, 0);
            }
        }
        __builtin_amdgcn_s_setprio(0);
        __syncthreads();
    }

#pragma unroll
    for (int mt = 0; mt < 2; mt++)
#pragma unroll
        for (int reg = 0; reg < 4; reg++) {
            float s = lsum[mt][reg];
#pragma unroll
            for (int off = 1; off < 16; off <<= 1) s += __shfl_xor(s, off, 64);
            lsum[mt][reg] = 1.f / s;
        }
#pragma unroll
    for (int mt = 0; mt < 2; mt++)
#pragma unroll
        for (int dt = 0; dt < 3; dt++)
#pragma unroll
            for (int reg = 0; reg < 4; reg++) {
                size_t row = (size_t)(b * NN + q0 + w * 32 + mt * 16 + quad * 4 + reg);
                out[row * DIM + h * HD + dt * 16 + l16] = f2bf_c(acc[mt][dt][reg] * lsum[mt][reg]);
            }
}

extern "C" void kernel_launch(void* const* d_in, const int* in_sizes, int n_in,
                              void* d_out, int out_size, void* d_ws, size_t ws_size,
                              hipStream_t stream) {
    const float* x   = (const float*)d_in[0];
    const float* pos = (const float*)d_in[1];
    const int*   mask= (const int*)  d_in[2];
    const float* Wq  = (const float*)d_in[3];
    const float* bq  = (const float*)d_in[4];
    const float* Wk  = (const float*)d_in[5];
    const float* bk  = (const float*)d_in[6];
    const float* Wv  = (const float*)d_in[7];
    const float* bv  = (const float*)d_in[8];
    const float* pw1 = (const float*)d_in[9];
    const float* pb1 = (const float*)d_in[10];
    const float* pw2 = (const float*)d_in[11];
    const float* pb2 = (const float*)d_in[12];
    const float* Wo  = (const float*)d_in[13];
    const float* bo  = (const float*)d_in[14];
    const float* mw1 = (const float*)d_in[15];
    const float* mb1 = (const float*)d_in[16];
    const float* mw2 = (const float*)d_in[17];
    const float* mb2 = (const float*)d_in[18];
    const float* g1  = (const float*)d_in[19];
    const float* be1 = (const float*)d_in[20];
    const float* g2  = (const float*)d_in[21];
    const float* be2 = (const float*)d_in[22];
    float* out = (float*)d_out;

    // workspace layout (bytes)
    char* wsb = (char*)d_ws;
    short* h_bf    = (short*)(wsb + 0);           // 6291456
    short* q_bf    = (short*)(wsb + 6291456);
    short* k_bf    = (short*)(wsb + 12582912);
    short* vt_bf   = (short*)(wsb + 18874368);    // V^T [b][h][d][n], key-permuted
    short* attn_bf = (short*)(wsb + 25165824);
    short* mlph_bf = h_bf;                        // overlays h|q|k|vt (dead by MLP1)
    float* pebuf   = (float*)(wsb + 31457280);    // 1572864
    float* x1      = (float*)(wsb + 33030144);    // 12582912
    short* h2_bf   = (short*)(wsb + 45613056);    // 6291456
    short* Wqkv_t  = (short*)(wsb + 51904512);    // [1152][384] bf16
    short* Wo_t    = (short*)(wsb + 52789248);    // [384][384]
    short* mw1_t   = (short*)(wsb + 53084160);    // [1536][384]
    short* mw2_t   = (short*)(wsb + 54263808);    // [384][1536]
    float* bqkv    = (float*)(wsb + 55443456);    // [1152]

    // --- fused head: weight prep + LN1 + pos-MLP (1 launch) ---
    head_kernel<<<5825, 256, 0, stream>>>(Wq, Wk, Wv, Wo, mw1, mw2, bq, bk, bv,
                                          x, g1, be1, pos, pw1, pb1, pw2, pb2,
                                          Wqkv_t, Wo_t, mw1_t, mw2_t, bqkv, h_bf, pebuf);

    // fused QKV: 64x64 blocks -> 2304 blocks (9/CU)
    gemm8_kernel<0, DIM><<<dim3(3 * DIM / 64, ROWS / 64), 256, 0, stream>>>(
        h_bf, Wqkv_t, bqkv, pebuf, nullptr, nullptr, nullptr, q_bf, k_bf, vt_bf,
        ROWS, 3 * DIM);

    // attention: 512 blocks of 128 queries, single-barrier dbuf pipeline
    attn7_kernel<<<dim3(NN / 128, HEADS, BB), 256, 0, stream>>>(
        q_bf, k_bf, vt_bf, mask, attn_bf);

    // Wo + residual + mask -> x1 fp32 (768 blocks, 3/CU)
    gemm8_kernel<2, DIM><<<dim3(DIM / 64, ROWS / 64), 256, 0, stream>>>(
        attn_bf, Wo_t, bo, nullptr, x, mask, x1, nullptr, nullptr, nullptr,
        ROWS, DIM);

    ln_bf16_kernel<<<ROWS / 4, 256, 0, stream>>>(x1, g2, be2, h2_bf);

    // MLP1 (exact gelu) -> bf16 hidden (3072 blocks)
    gemm8_kernel<1, DIM><<<dim3(MLPH / 64, ROWS / 64), 256, 0, stream>>>(
        h2_bf, mw1_t, mb1, nullptr, nullptr, nullptr, nullptr, mlph_bf, nullptr, nullptr,
        ROWS, MLPH);

    // MLP2 + residual + mask -> out fp32 (768 blocks)
    gemm8_kernel<3, MLPH><<<dim3(DIM / 64, ROWS / 64), 256, 0, stream>>>(
        mlph_bf, mw2_t, mb2, nullptr, x1, mask, out, nullptr, nullptr, nullptr,
        ROWS, DIM);
}

// Round 6
// 242.099 us; speedup vs baseline: 1.0682x; 1.0682x over previous
//
#include <hip/hip_runtime.h>
#include <hip/hip_bf16.h>
#include <math.h>

// Problem constants
#define BB 4
#define NN 2048
#define DIM 384
#define HEADS 8
#define HD 48
#define MLPH 1536
#define ROWS (BB*NN)          // 8192
#define SZ ((size_t)ROWS*DIM) // 3145728 elems per (B,N,DIM) buffer

typedef float floatx4 __attribute__((ext_vector_type(4)));
typedef short shortx8 __attribute__((ext_vector_type(8)));

__device__ __forceinline__ float gelu_exact(float x) {
    return 0.5f * x * (1.0f + erff(x * 0.70710678118654752f));
}

__device__ __forceinline__ short f2bf(float f) {
    __hip_bfloat16 h = __float2bfloat16(f);
    return *reinterpret_cast<short*>(&h);
}

// packed f32x2 -> bf16x2 in one VALU op (low = a, high = b)
__device__ __forceinline__ unsigned cvtpk(float a, float b) {
    unsigned r;
    asm("v_cvt_pk_bf16_f32 %0, %1, %2" : "=v"(r) : "v"(a), "v"(b));
    return r;
}
__device__ __forceinline__ short f2bf_c(float f) {
    return (short)((__float_as_uint(f) + 0x8000u) >> 16);
}

// async global->LDS 16B: linear LDS dest (base + lane*16), per-lane global src
typedef __attribute__((address_space(3))) void lds_void;
typedef const __attribute__((address_space(1))) void gbl_void;
__device__ __forceinline__ void gload16(const void* g, void* l) {
    __builtin_amdgcn_global_load_lds((gbl_void*)g, (lds_void*)l, 16, 0, 0);
}

// softmax scale folded with log2(e): q is pre-scaled so attn uses bare exp2
#define SCALE_Q 0.20823510128640994f  // (1/sqrt(48)) * log2(e)

// ---------------- LayerNorm: 4 rows/block (one wave each), fp32 -> bf16 ----------------
__global__ __launch_bounds__(256) void ln_bf16_kernel(const float* __restrict__ x,
                                                      const float* __restrict__ g,
                                                      const float* __restrict__ be,
                                                      short* __restrict__ out) {
    int row = blockIdx.x * 4 + (threadIdx.x >> 6);
    int lane = threadIdx.x & 63;
    const float* xp = x + (size_t)row * DIM;
    float v[6];
    float sum = 0.f, sumsq = 0.f;
#pragma unroll
    for (int j = 0; j < 6; j++) {
        float val = xp[lane + j * 64];
        v[j] = val; sum += val; sumsq += val * val;
    }
#pragma unroll
    for (int off = 1; off < 64; off <<= 1) {
        sum += __shfl_xor(sum, off, 64);
        sumsq += __shfl_xor(sumsq, off, 64);
    }
    float mean = sum * (1.f / DIM);
    float var = sumsq * (1.f / DIM) - mean * mean;
    float rstd = rsqrtf(var + 1e-5f);
    short* op = out + (size_t)row * DIM;
#pragma unroll
    for (int j = 0; j < 6; j++) {
        int c = lane + j * 64;
        op[c] = f2bf((v[j] - mean) * rstd * g[c] + be[c]);
    }
}

// ---------------- fused head: weight transposes + bias concat + LN1 + pos-MLP ----------
__global__ __launch_bounds__(256) void head_kernel(const float* __restrict__ Wq,
                                                   const float* __restrict__ Wk,
                                                   const float* __restrict__ Wv,
                                                   const float* __restrict__ Wo,
                                                   const float* __restrict__ mw1,
                                                   const float* __restrict__ mw2,
                                                   const float* __restrict__ bq,
                                                   const float* __restrict__ bk,
                                                   const float* __restrict__ bv,
                                                   const float* __restrict__ x,
                                                   const float* __restrict__ g1,
                                                   const float* __restrict__ be1,
                                                   const float* __restrict__ pos,
                                                   const float* __restrict__ pw1,
                                                   const float* __restrict__ pb1,
                                                   const float* __restrict__ pw2,
                                                   const float* __restrict__ pb2,
                                                   short* __restrict__ Wqkv_t,
                                                   short* __restrict__ Wo_t,
                                                   short* __restrict__ mw1_t,
                                                   short* __restrict__ mw2_t,
                                                   float* __restrict__ bqkv,
                                                   short* __restrict__ h_bf,
                                                   float* __restrict__ pe) {
    __shared__ float tile[32][33];
    __shared__ float pw2s[HD * HD];
    __shared__ float hsh[4][HD];
    const int id = blockIdx.x;
    const int t = threadIdx.x;
    if (id < 1728) {
        const float* src; short* dst; int K, N, tid;
        if (id < 144)       { src = Wq;  dst = Wqkv_t;          K = 384;  N = 384;  tid = id; }
        else if (id < 288)  { src = Wk;  dst = Wqkv_t + 147456; K = 384;  N = 384;  tid = id - 144; }
        else if (id < 432)  { src = Wv;  dst = Wqkv_t + 294912; K = 384;  N = 384;  tid = id - 288; }
        else if (id < 576)  { src = Wo;  dst = Wo_t;            K = 384;  N = 384;  tid = id - 432; }
        else if (id < 1152) { src = mw1; dst = mw1_t;           K = 384;  N = 1536; tid = id - 576; }
        else                { src = mw2; dst = mw2_t;           K = 1536; N = 384;  tid = id - 1152; }
        int ntx = N / 32;
        int n0 = (tid % ntx) * 32, k0 = (tid / ntx) * 32;
        int c = t & 31, r4 = t >> 5;
#pragma unroll
        for (int i = 0; i < 4; i++) {
            int r = r4 + i * 8;
            tile[r][c] = src[(size_t)(k0 + r) * N + n0 + c];
        }
        __syncthreads();
#pragma unroll
        for (int i = 0; i < 4; i++) {
            int r = r4 + i * 8;
            dst[(size_t)(n0 + r) * K + k0 + c] = f2bf(tile[c][r]);
        }
    } else if (id == 1728) {
        for (int i = t; i < 3 * DIM; i += 256)
            bqkv[i] = i < DIM ? bq[i] : (i < 2 * DIM ? bk[i - DIM] : bv[i - 2 * DIM]);
    } else if (id < 3777) {
        int row = (id - 1729) * 4 + (t >> 6);
        int lane = t & 63;
        const float* xp = x + (size_t)row * DIM;
        float v[6];
        float sum = 0.f, sumsq = 0.f;
#pragma unroll
        for (int j = 0; j < 6; j++) {
            float val = xp[lane + j * 64];
            v[j] = val; sum += val; sumsq += val * val;
        }
#pragma unroll
        for (int off = 1; off < 64; off <<= 1) {
            sum += __shfl_xor(sum, off, 64);
            sumsq += __shfl_xor(sumsq, off, 64);
        }
        float mean = sum * (1.f / DIM);
        float var = sumsq * (1.f / DIM) - mean * mean;
        float rstd = rsqrtf(var + 1e-5f);
        short* op = h_bf + (size_t)row * DIM;
#pragma unroll
        for (int j = 0; j < 6; j++) {
            int c = lane + j * 64;
            op[c] = f2bf((v[j] - mean) * rstd * g1[c] + be1[c]);
        }
    } else {
        int w = t >> 6, lane = t & 63;
        int p = (id - 3777) * 4 + w;
        for (int i = t; i < HD * HD; i += 256) pw2s[i] = pw2[i];
        float px = pos[(size_t)p * 3 + 0];
        float py = pos[(size_t)p * 3 + 1];
        float pz = pos[(size_t)p * 3 + 2];
        __syncthreads();
        if (lane < HD) {
            float hv = px * pw1[0 * HD + lane] + py * pw1[1 * HD + lane] + pz * pw1[2 * HD + lane] + pb1[lane];
            hsh[w][lane] = gelu_exact(hv);
        }
        if (lane < HD) {
            float o = pb2[lane];
#pragma unroll 8
            for (int i = 0; i < HD; i++) o += hsh[w][i] * pw2s[i * HD + lane];
            pe[(size_t)p * HD + lane] = o;
        }
    }
}

// ---------------- bf16 MFMA GEMM v7x: gemm7 + XCD-aware block swizzle ----------------
// Same as round-4 gemm7 (dbuf global_load_lds, 1 barrier/K-step) plus T1: remap the
// flat block id so each XCD gets a CONTIGUOUS chunk of the logical tile order
// (consecutive logical tiles share A-panels -> per-XCD L2 hits instead of 8-way
// HBM refetch). All grids used are divisible by 8 -> simple form is bijective.
// MODE 0: QKV fused -> q/k row-major bf16 (q pre-scaled by SCALE_Q; pe added to k),
//         V^T permuted (key_new = 4*(key%16)+key/16 per 64-key tile).
// MODE 1: exact gelu -> bf16 (MLP1)
// MODE 2: of = res + (mask ? v : 0)  fp32 (Wo + residual)
// MODE 3: of = mask ? (res + v) : 0  fp32 (MLP2 + residual + mask)
template <int MODE>
__global__ __launch_bounds__(256) void gemm7_kernel(const short* __restrict__ A,
                                                    const short* __restrict__ Bt,
                                                    const float* __restrict__ bias,
                                                    const float* __restrict__ pe,
                                                    const float* __restrict__ res,
                                                    const int* __restrict__ mask,
                                                    float* __restrict__ of,
                                                    short* __restrict__ o0,
                                                    short* __restrict__ o1,
                                                    short* __restrict__ o2,
                                                    int M, int N, int K) {
    __shared__ short As[2][64 * 64];
    __shared__ short Bs[2][64 * 64];
    const int t = threadIdx.x, lane = t & 63, w = t >> 6;
    const int l16 = lane & 15, quad = lane >> 4;

    // XCD swizzle: HW flat id -> logical tile id (contiguous chunk per XCD)
    const int nwg = gridDim.x * gridDim.y;
    int flat = blockIdx.y * gridDim.x + blockIdx.x;
    flat = (flat & 7) * (nwg >> 3) + (flat >> 3);
    const int m0 = (flat / gridDim.x) * 64, n0 = (flat % gridDim.x) * 64;
    const int wm = (w & 1) * 32, wn = (w >> 1) * 32;

    // staging: wave w covers tile rows [w*16, w*16+16), 2 DMA instrs each for A and B.
    // lane ll -> row w*16 + i*8 + (ll>>3), LDS chunk ll&7 (linear),
    // global chunk (ll&7)^(ll>>3)  [inverse swizzle -> content matches (c^(r&7)) reads]
    const int rA = lane >> 3;
    const int csw = ((lane & 7) ^ rA) * 8;
    const short* gAl = A + (size_t)(m0 + w * 16 + rA) * K + csw;
    const short* gBl = Bt + (size_t)(n0 + w * 16 + rA) * K + csw;
    const int ldsb = w * 16 * 64;   // wave's row base (shorts)

    floatx4 acc[2][2] = {};
    const int sA = l16 & 7;

#define STAGE7(buf, k0off)                                              \
    do {                                                                \
        gload16(gAl + (k0off), &As[buf][ldsb]);                         \
        gload16(gAl + 8 * K + (k0off), &As[buf][ldsb + 8 * 64]);        \
        gload16(gBl + (k0off), &Bs[buf][ldsb]);                         \
        gload16(gBl + 8 * K + (k0off), &Bs[buf][ldsb + 8 * 64]);        \
    } while (0)

    STAGE7(0, 0);
    int cur = 0;
    for (int k0 = 0; k0 < K; k0 += 64) {
        __syncthreads();                 // vmcnt(0) drain: buf[cur] ready; prior reads done
        if (k0 + 64 < K) STAGE7(cur ^ 1, k0 + 64);
        const short* Ac = As[cur];
        const short* Bc = Bs[cur];
#pragma unroll
        for (int kkc = 0; kkc < 2; kkc++) {
            shortx8 af[2], bfr[2];
            int slot = ((quad + kkc * 4) ^ sA) * 8;
#pragma unroll
            for (int i = 0; i < 2; i++) {
                af[i]  = *(const shortx8*)&Ac[(wm + i * 16 + l16) * 64 + slot];
                bfr[i] = *(const shortx8*)&Bc[(wn + i * 16 + l16) * 64 + slot];
            }
#pragma unroll
            for (int mi = 0; mi < 2; mi++)
#pragma unroll
                for (int ni = 0; ni < 2; ni++)
                    acc[mi][ni] = __builtin_amdgcn_mfma_f32_16x16x32_bf16(af[mi], bfr[ni], acc[mi][ni], 0, 0, 0);
        }
        cur ^= 1;
    }
#undef STAGE7

    // epilogue: C row = m0+wm+mi*16+quad*4+reg, col = n0+wn+ni*16+l16
    const int seg = (MODE == 0) ? (n0 / DIM) : 0;
#pragma unroll
    for (int mi = 0; mi < 2; mi++) {
        int mrow0 = m0 + wm + mi * 16 + quad * 4;
        int4 mk4 = {0, 0, 0, 0};
        if (MODE == 2 || MODE == 3) mk4 = *(const int4*)&mask[mrow0];
#pragma unroll
        for (int ni = 0; ni < 2; ni++) {
            int n = n0 + wn + ni * 16 + l16;
            float bv = bias[n];
            float vals[4];
#pragma unroll
            for (int reg = 0; reg < 4; reg++) vals[reg] = acc[mi][ni][reg] + bv;
            if (MODE == 0) {
                int nl = n - seg * DIM;
                if (seg == 2) {
                    // V^T [b,h,d,T*64+key_new], key_new = 4*(key%16)+key/16
                    int hh = nl / HD, d = nl - hh * HD;
                    int bb = mrow0 / NN, nb = mrow0 - bb * NN;
                    int T = nb >> 6, ko = nb & 63;
                    int c16 = ko & 15, kb = ko >> 4;
                    short* vp = o2 + ((size_t)((bb * HEADS + hh) * HD + d)) * NN + T * 64 + kb;
#pragma unroll
                    for (int reg = 0; reg < 4; reg++) vp[4 * (c16 + reg)] = f2bf(vals[reg]);
                } else {
                    short* dstq = (seg == 0) ? o0 : o1;
                    int pc = nl % HD;
#pragma unroll
                    for (int reg = 0; reg < 4; reg++) {
                        int m = mrow0 + reg;
                        float val = vals[reg];
                        if (seg == 0) val *= SCALE_Q;       // fold softmax scale + log2e into q
                        if (seg == 1) val += pe[(size_t)m * HD + pc];
                        dstq[(size_t)m * DIM + nl] = f2bf(val);
                    }
                }
            } else if (MODE == 1) {
#pragma unroll
                for (int reg = 0; reg < 4; reg++)
                    o0[(size_t)(mrow0 + reg) * N + n] = f2bf(gelu_exact(vals[reg]));
            } else if (MODE == 2) {
#pragma unroll
                for (int reg = 0; reg < 4; reg++) {
                    int m = mrow0 + reg;
                    int mk = ((const int*)&mk4)[reg];
                    of[(size_t)m * N + n] = res[(size_t)m * N + n] + (mk ? vals[reg] : 0.f);
                }
            } else {
#pragma unroll
                for (int reg = 0; reg < 4; reg++) {
                    int m = mrow0 + reg;
                    int mk = ((const int*)&mk4)[reg];
                    of[(size_t)m * N + n] = mk ? (res[(size_t)m * N + n] + vals[reg]) : 0.f;
                }
            }
        }
    }
}

// ---------------- MFMA flash attention v8x: v8 + XCD-aware block swizzle -------------
// T1: each (b,h)'s 16 q-tile blocks share a 384 KB K/V panel; the swizzle lands each
// (b,h) group on ONE XCD (chunk of 64 flat ids = 4 full groups per XCD) so the panel
// is fetched per-XCD-once instead of 8-way scattered (FETCH 52 MB vs 19 MB unique).
// q arrives pre-scaled by (1/sqrt(HD))*log2(e):
//   P = exp2(q'.k + ad),  ad = 0 / -1e30  (key-mask bias, folded into MFMA C input
//   since C/D col = l16 = key is lane-constant). bf16 pack via v_cvt_pk_bf16_f32.
__global__ __launch_bounds__(256) void attn7_kernel(const short* __restrict__ q,
                                                    const short* __restrict__ k,
                                                    const short* __restrict__ vt,
                                                    const int* __restrict__ mask,
                                                    short* __restrict__ out) {
    // XCD swizzle over 512 blocks: chunk = 64 per XCD
    int flat = (blockIdx.z * gridDim.y + blockIdx.y) * gridDim.x + blockIdx.x;
    flat = (flat & 7) * 64 + (flat >> 3);
    const int b = flat >> 7, h = (flat >> 4) & 7;
    const int q0 = (flat & 15) * 128;
    const int t = threadIdx.x;
    const int lane = t & 63;
    const int w = t >> 6;
    const int l16 = lane & 15;
    const int quad = lane >> 4;

    __shared__ __align__(16) short SH[23552];
    __shared__ float madd2[2][64];

    {
        int buf = t >> 7, r = (t >> 1) & 63, zc = 6 + (t & 1);
        shortx8 z = {0, 0, 0, 0, 0, 0, 0, 0};
        *(shortx8*)&SH[buf * 4096 + r * 64 + ((zc ^ (r & 7)) * 8)] = z;
    }

    const size_t vtbase = (size_t)((b * HEADS + h) * HD) * NN;
    const short* gsrc[3]; int loff[3]; int gstep[3]; int bstr[3];
#pragma unroll
    for (int i = 0; i < 3; i++) {
        int u = t + i * 256;
        if (u < 384) {
            int r = u / 6, c = u - r * 6;
            gsrc[i] = k + ((size_t)(b * NN + r)) * DIM + h * HD + c * 8;
            gstep[i] = 64 * DIM;
            loff[i] = r * 64 + ((c ^ (r & 7)) * 8);
            bstr[i] = 4096;
        } else {
            int uu = u - 384;
            int d = uu >> 3, ck = uu & 7;
            gsrc[i] = vt + vtbase + (size_t)d * NN + ck * 8;
            gstep[i] = 64;
            loff[i] = 8192 + d * 64 + ((ck ^ (d & 7)) * 8);
            bstr[i] = 3072;
        }
    }

    shortx8 pre[3];
#pragma unroll
    for (int i = 0; i < 3; i++) pre[i] = *(const shortx8*)gsrc[i];
#pragma unroll
    for (int i = 0; i < 3; i++) *(shortx8*)&SH[loff[i]] = pre[i];
    if (t < 64) madd2[0][t] = mask[b * NN + t] ? 0.f : -1e30f;
#pragma unroll
    for (int i = 0; i < 3; i++) { gsrc[i] += gstep[i]; pre[i] = *(const shortx8*)gsrc[i]; }
    int mreg = (t < 64) ? mask[b * NN + 64 + t] : 0;

    shortx8 qf[2][2];
#pragma unroll
    for (int mt = 0; mt < 2; mt++) {
        const short* qp = q + ((size_t)(b * NN + q0 + w * 32 + mt * 16 + l16)) * DIM + h * HD;
        qf[mt][0] = *(const shortx8*)&qp[quad * 8];
        if (quad < 2) qf[mt][1] = *(const shortx8*)&qp[32 + quad * 8];
        else          qf[mt][1] = (shortx8){0, 0, 0, 0, 0, 0, 0, 0};
    }

    floatx4 acc[2][3] = {};
    float lsum[2][4] = {};
    const float cs = 0.14433756729740643f;
    const int plb = 14336 + w * 2304;
    const int sw = (l16 & 7);

    __syncthreads();

    for (int kt = 0; kt < 32; kt++) {
        const int cur = kt & 1, nxt = cur ^ 1;
        const int kso = cur * 4096, vto = 8192 + cur * 3072;

        shortx8 kb[4][2];
#pragma unroll
        for (int nt = 0; nt < 4; nt++) {
            int r = nt * 16 + l16;
            kb[nt][0] = *(const shortx8*)&SH[kso + r * 64 + ((quad ^ sw) * 8)];
            kb[nt][1] = *(const shortx8*)&SH[kso + r * 64 + (((4 + quad) ^ sw) * 8)];
        }
        float ad[4];
#pragma unroll
        for (int nt = 0; nt < 4; nt++) ad[nt] = madd2[cur][nt * 16 + l16];

        if (kt < 31) {
#pragma unroll
            for (int i = 0; i < 3; i++) *(shortx8*)&SH[loff[i] + nxt * bstr[i]] = pre[i];
            if (t < 64) madd2[nxt][t] = mreg ? 0.f : -1e30f;
            if (kt < 30) {
#pragma unroll
                for (int i = 0; i < 3; i++) { gsrc[i] += gstep[i]; pre[i] = *(const shortx8*)gsrc[i]; }
                if (t < 64) mreg = mask[b * NN + (kt + 2) * 64 + t];
            }
        }

        floatx4 S[2][4];
        __builtin_amdgcn_s_setprio(1);
#pragma unroll
        for (int nt = 0; nt < 4; nt++) {
            floatx4 ci = {ad[nt], ad[nt], ad[nt], ad[nt]};
#pragma unroll
            for (int mt = 0; mt < 2; mt++) {
                floatx4 s = __builtin_amdgcn_mfma_f32_16x16x32_bf16(qf[mt][0], kb[nt][0], ci, 0, 0, 0);
                s = __builtin_amdgcn_mfma_f32_16x16x32_bf16(qf[mt][1], kb[nt][1], s, 0, 0, 0);
                S[mt][nt] = s;
            }
        }
        __builtin_amdgcn_s_setprio(0);
#pragma unroll
        for (int mt = 0; mt < 2; mt++) {
            float p[4][4];
#pragma unroll
            for (int nt = 0; nt < 4; nt++) {
#pragma unroll
                for (int reg = 0; reg < 4; reg++) {
                    float pv = __builtin_amdgcn_exp2f(S[mt][nt][reg]);
                    p[nt][reg] = pv;
                    lsum[mt][reg] += pv;
                }
            }
#pragma unroll
            for (int reg = 0; reg < 4; reg++) {
                *(uint2*)&SH[plb + (mt * 16 + quad * 4 + reg) * 72 + l16 * 4] =
                    make_uint2(cvtpk(p[0][reg], p[1][reg]), cvtpk(p[2][reg], p[3][reg]));
            }
        }
        __builtin_amdgcn_s_setprio(1);
#pragma unroll
        for (int c = 0; c < 2; c++) {
            shortx8 pf[2];
#pragma unroll
            for (int mt = 0; mt < 2; mt++)
                pf[mt] = *(const shortx8*)&SH[plb + (mt * 16 + l16) * 72 + c * 32 + quad * 8];
#pragma unroll
            for (int dt = 0; dt < 3; dt++) {
                shortx8 vf = *(const shortx8*)&SH[vto + (dt * 16 + l16) * 64 + (((c * 4 + quad) ^ sw) * 8)];
#pragma unroll
                for (int mt = 0; mt < 2; mt++)
                    acc[mt][dt] = __builtin_amdgcn_mfma_f32_16x16x32_bf16(pf[mt], vf, acc[mt][dt], 0, 0, 0);
            }
        }
        __builtin_amdgcn_s_setprio(0);
        __syncthreads();
    }

#pragma unroll
    for (int mt = 0; mt < 2; mt++)
#pragma unroll
        for (int reg = 0; reg < 4; reg++) {
            float s = lsum[mt][reg];
#pragma unroll
            for (int off = 1; off < 16; off <<= 1) s += __shfl_xor(s, off, 64);
            lsum[mt][reg] = 1.f / s;
        }
#pragma unroll
    for (int mt = 0; mt < 2; mt++)
#pragma unroll
        for (int dt = 0; dt < 3; dt++)
#pragma unroll
            for (int reg = 0; reg < 4; reg++) {
                size_t row = (size_t)(b * NN + q0 + w * 32 + mt * 16 + quad * 4 + reg);
                out[row * DIM + h * HD + dt * 16 + l16] = f2bf_c(acc[mt][dt][reg] * lsum[mt][reg]);
            }
}

extern "C" void kernel_launch(void* const* d_in, const int* in_sizes, int n_in,
                              void* d_out, int out_size, void* d_ws, size_t ws_size,
                              hipStream_t stream) {
    const float* x   = (const float*)d_in[0];
    const float* pos = (const float*)d_in[1];
    const int*   mask= (const int*)  d_in[2];
    const float* Wq  = (const float*)d_in[3];
    const float* bq  = (const float*)d_in[4];
    const float* Wk  = (const float*)d_in[5];
    const float* bk  = (const float*)d_in[6];
    const float* Wv  = (const float*)d_in[7];
    const float* bv  = (const float*)d_in[8];
    const float* pw1 = (const float*)d_in[9];
    const float* pb1 = (const float*)d_in[10];
    const float* pw2 = (const float*)d_in[11];
    const float* pb2 = (const float*)d_in[12];
    const float* Wo  = (const float*)d_in[13];
    const float* bo  = (const float*)d_in[14];
    const float* mw1 = (const float*)d_in[15];
    const float* mb1 = (const float*)d_in[16];
    const float* mw2 = (const float*)d_in[17];
    const float* mb2 = (const float*)d_in[18];
    const float* g1  = (const float*)d_in[19];
    const float* be1 = (const float*)d_in[20];
    const float* g2  = (const float*)d_in[21];
    const float* be2 = (const float*)d_in[22];
    float* out = (float*)d_out;

    // workspace layout (bytes)
    char* wsb = (char*)d_ws;
    short* h_bf    = (short*)(wsb + 0);           // 6291456
    short* q_bf    = (short*)(wsb + 6291456);
    short* k_bf    = (short*)(wsb + 12582912);
    short* vt_bf   = (short*)(wsb + 18874368);    // V^T [b][h][d][n], key-permuted
    short* attn_bf = (short*)(wsb + 25165824);
    short* mlph_bf = h_bf;                        // overlays h|q|k|vt (dead by MLP1)
    float* pebuf   = (float*)(wsb + 31457280);    // 1572864
    float* x1      = (float*)(wsb + 33030144);    // 12582912
    short* h2_bf   = (short*)(wsb + 45613056);    // 6291456
    short* Wqkv_t  = (short*)(wsb + 51904512);    // [1152][384] bf16
    short* Wo_t    = (short*)(wsb + 52789248);    // [384][384]
    short* mw1_t   = (short*)(wsb + 53084160);    // [1536][384]
    short* mw2_t   = (short*)(wsb + 54263808);    // [384][1536]
    float* bqkv    = (float*)(wsb + 55443456);    // [1152]

    // --- fused head: weight prep + LN1 + pos-MLP (1 launch) ---
    head_kernel<<<5825, 256, 0, stream>>>(Wq, Wk, Wv, Wo, mw1, mw2, bq, bk, bv,
                                          x, g1, be1, pos, pw1, pb1, pw2, pb2,
                                          Wqkv_t, Wo_t, mw1_t, mw2_t, bqkv, h_bf, pebuf);

    // fused QKV: 64x64 blocks -> 2304 blocks (9/CU)
    gemm7_kernel<0><<<dim3(3 * DIM / 64, ROWS / 64), 256, 0, stream>>>(
        h_bf, Wqkv_t, bqkv, pebuf, nullptr, nullptr, nullptr, q_bf, k_bf, vt_bf,
        ROWS, 3 * DIM, DIM);

    // attention: 512 blocks of 128 queries, single-barrier dbuf pipeline
    attn7_kernel<<<dim3(NN / 128, HEADS, BB), 256, 0, stream>>>(
        q_bf, k_bf, vt_bf, mask, attn_bf);

    // Wo + residual + mask -> x1 fp32 (768 blocks, 3/CU)
    gemm7_kernel<2><<<dim3(DIM / 64, ROWS / 64), 256, 0, stream>>>(
        attn_bf, Wo_t, bo, nullptr, x, mask, x1, nullptr, nullptr, nullptr,
        ROWS, DIM, DIM);

    ln_bf16_kernel<<<ROWS / 4, 256, 0, stream>>>(x1, g2, be2, h2_bf);

    // MLP1 (exact gelu) -> bf16 hidden (3072 blocks)
    gemm7_kernel<1><<<dim3(MLPH / 64, ROWS / 64), 256, 0, stream>>>(
        h2_bf, mw1_t, mb1, nullptr, nullptr, nullptr, nullptr, mlph_bf, nullptr, nullptr,
        ROWS, MLPH, DIM);

    // MLP2 + residual + mask -> out fp32 (768 blocks)
    gemm7_kernel<3><<<dim3(DIM / 64, ROWS / 64), 256, 0, stream>>>(
        mlph_bf, mw2_t, mb2, nullptr, x1, mask, out, nullptr, nullptr, nullptr,
        ROWS, DIM, MLPH);
}